// Round 6
// baseline (228.319 us; speedup 1.0000x reference)
//
#include <hip/hip_runtime.h>
#include <hip/hip_bf16.h>
#include <math.h>

#define B_  32
#define T_  128
#define NF_ 20
#define D_  512
#define S_  5
#define L_  96
#define EPS_ 1e-8f
#define NSEG (B_ * L_)                       // 3072
#define NPOS (NF_ - 1)                       // 19
#define NELEM (NF_ * D_)                     // 10240 floats = 40 KB
#define RPAD (D_ + 8)                        // padded row (shorts): breaks pow2 bank stride
#define GLD 33                               // Gram leading dim (fp32)
#define SPB 4                                // segments per block (pipelined)
#define NBLK (NSEG / SPB)                    // 768 = 3 blocks/CU exactly resident

typedef short short8 __attribute__((ext_vector_type(8)));
typedef float f32x4  __attribute__((ext_vector_type(4)));

__device__ __forceinline__ unsigned f2bf2(float lo, float hi) {
  // round-to-nearest-even bf16, packed pair (lo in bits [15:0])
  unsigned ulo = __float_as_uint(lo);
  ulo += 0x7fffu + ((ulo >> 16) & 1u);
  unsigned uhi = __float_as_uint(hi);
  uhi += 0x7fffu + ((uhi >> 16) & 1u);
  return (uhi & 0xffff0000u) | (ulo >> 16);
}

__global__ __launch_bounds__(256) void phoneme_ssl_seg_kernel(
    const float* __restrict__ out,
    const int* __restrict__ batch_idx,
    const int* __restrict__ time_idx,
    const int* __restrict__ neg_idx,
    float* __restrict__ partials) {

  __shared__ __align__(16) unsigned short V[2][NF_ * RPAD];  // 2 x 20800 B
  __shared__ float G[2][32 * GLD];                           // 2 x 4224 B

  const int wave = threadIdx.x >> 6;
  const int lane = threadIdx.x & 63;
  const int r = lane & 15;
  const int q = lane >> 4;                   // quad: k = q*8 + j
  const int rowA = (wave >= 2) ? ((16 + r > 19) ? 19 : 16 + r) : r;
  const int rowB = (wave & 1)  ? ((16 + r > 19) ? 19 : 16 + r) : r;
  const int rbase = (wave >= 2) ? 16 : 0;
  const int cbase = (wave & 1) ? 16 : 0;

  // hoist negative indices (wave-0 softmax lanes only)
  int nidx[S_];
  if (threadIdx.x < NPOS) {
#pragma unroll
    for (int j = 0; j < S_; ++j) nidx[j] = neg_idx[threadIdx.x * S_ + j];
  }

  // ---- stage segment 0 into V[0] ----
  {
    const int n0 = blockIdx.x * SPB;
    const float4* __restrict__ src4 =
        (const float4*)(out + (size_t)(batch_idx[n0] * T_ + time_idx[n0]) * NELEM);
#pragma unroll
    for (int it = 0; it < 5; ++it) {
      const int c = threadIdx.x + 256 * it;
      const float4 x = src4[2 * c];
      const float4 y = src4[2 * c + 1];
      uint4 w;
      w.x = f2bf2(x.x, x.y); w.y = f2bf2(x.z, x.w);
      w.z = f2bf2(y.x, y.y); w.w = f2bf2(y.z, y.w);
      *(uint4*)&V[0][(c >> 6) * RPAD + (c & 63) * 8] = w;
    }
  }
  __syncthreads();

  float local = 0.f;
#pragma unroll
  for (int s = 0; s < SPB; ++s) {
    const int cur = s & 1, nxt = cur ^ 1;

    // 1. prefetch global loads for seg s+1 (in flight during Gram below)
    float4 pf[10];
    if (s + 1 < SPB) {
      const int n1 = blockIdx.x * SPB + s + 1;
      const float4* __restrict__ src4 =
          (const float4*)(out + (size_t)(batch_idx[n1] * T_ + time_idx[n1]) * NELEM);
#pragma unroll
      for (int it = 0; it < 5; ++it) {
        const int c = threadIdx.x + 256 * it;
        pf[2 * it]     = src4[2 * c];
        pf[2 * it + 1] = src4[2 * c + 1];
      }
    }

    // 2. Gram via MFMA, one 16x16 C-tile per wave: G = V * V^T
    {
      const unsigned short* pA = &V[cur][rowA * RPAD + q * 8];
      const unsigned short* pB = &V[cur][rowB * RPAD + q * 8];
      f32x4 acc = {0.f, 0.f, 0.f, 0.f};
#pragma unroll
      for (int ks = 0; ks < D_ / 32; ++ks) {
        const short8 a = *(const short8*)(pA + 32 * ks);
        const short8 bb = (wave == 0 || wave == 3)
                            ? a : *(const short8*)(pB + 32 * ks);
        acc = __builtin_amdgcn_mfma_f32_16x16x32_bf16(a, bb, acc, 0, 0, 0);
      }
      // C/D layout (verified): col = lane&15, row = (lane>>4)*4 + reg
#pragma unroll
      for (int reg = 0; reg < 4; ++reg)
        G[cur][(rbase + q * 4 + reg) * GLD + cbase + r] = acc[reg];
    }

    // 3. pack + LDS-write seg s+1 into V[nxt]
    if (s + 1 < SPB) {
#pragma unroll
      for (int it = 0; it < 5; ++it) {
        const int c = threadIdx.x + 256 * it;
        uint4 w;
        w.x = f2bf2(pf[2 * it].x,     pf[2 * it].y);
        w.y = f2bf2(pf[2 * it].z,     pf[2 * it].w);
        w.z = f2bf2(pf[2 * it + 1].x, pf[2 * it + 1].y);
        w.w = f2bf2(pf[2 * it + 1].z, pf[2 * it + 1].w);
        *(uint4*)&V[nxt][(c >> 6) * RPAD + (c & 63) * 8] = w;
      }
    }

    // single barrier per segment: G[cur] complete + V[nxt] staged
    __syncthreads();

    // 4. softmax on G[cur] (wave 0 lanes 0..18) — overlaps next Gram of waves 1-3
    if (threadIdx.x < NPOS) {
      const int i = threadIdx.x;
      const float* __restrict__ Gc = G[cur];
      const float na = sqrtf(Gc[i * GLD + i]);
      float sims[1 + S_];
      {
        const float nb = sqrtf(Gc[(i + 1) * GLD + (i + 1)]);
        sims[0] = Gc[i * GLD + (i + 1)] / fmaxf(na * nb, EPS_);
      }
#pragma unroll
      for (int j = 0; j < S_; ++j) {
        const int f = nidx[j];
        const float nb = sqrtf(Gc[f * GLD + f]);
        sims[1 + j] = Gc[i * GLD + f] / fmaxf(na * nb, EPS_);
      }
      float m = sims[0];
#pragma unroll
      for (int j = 1; j < 1 + S_; ++j) m = fmaxf(m, sims[j]);
      float se = 0.f;
#pragma unroll
      for (int j = 0; j < 1 + S_; ++j) se += __expf(sims[j] - m);
      local += -(sims[0] - (m + __logf(se)));   // -log_softmax[...,0]
    }
  }

  // ---- wave-0 reduce + one plain store per block ----
  if (threadIdx.x < 64) {
#pragma unroll
    for (int off = 32; off >= 1; off >>= 1)
      local += __shfl_xor(local, off, 64);
    if (threadIdx.x == 0)
      partials[blockIdx.x] = local;
  }
}

__global__ __launch_bounds__(256) void phoneme_ssl_reduce_kernel(
    const float* __restrict__ partials, float* __restrict__ loss_out) {
  float acc = 0.f;
  for (int i = threadIdx.x; i < NBLK; i += 256) acc += partials[i];
#pragma unroll
  for (int off = 32; off >= 1; off >>= 1)
    acc += __shfl_xor(acc, off, 64);
  __shared__ float ws[4];
  if ((threadIdx.x & 63) == 0) ws[threadIdx.x >> 6] = acc;
  __syncthreads();
  if (threadIdx.x == 0)
    loss_out[0] = (ws[0] + ws[1] + ws[2] + ws[3]) * (1.0f / (float)(NSEG * NPOS));
}

extern "C" void kernel_launch(void* const* d_in, const int* in_sizes, int n_in,
                              void* d_out, int out_size, void* d_ws, size_t ws_size,
                              hipStream_t stream) {
  const float* out_t    = (const float*)d_in[0];
  const int* batch_idx  = (const int*)d_in[1];
  const int* time_idx   = (const int*)d_in[2];
  const int* neg_idx    = (const int*)d_in[3];
  float* loss_out       = (float*)d_out;
  float* partials       = (float*)d_ws;      // NBLK floats, fully overwritten each call

  phoneme_ssl_seg_kernel<<<NBLK, 256, 0, stream>>>(
      out_t, batch_idx, time_idx, neg_idx, partials);
  phoneme_ssl_reduce_kernel<<<1, 256, 0, stream>>>(partials, loss_out);
}